// Round 1
// baseline (287.994 us; speedup 1.0000x reference)
//
#include <hip/hip_runtime.h>

// SigJoin (Chen's identity), D=8, M=6, BATCH=128.
// z_k[j] = x_k[j] + y[lastdigit(j)] * S(j>>3 digits) , S shared per float4 group.
// Level start offsets O_i = (8^i - 8)/7: 0, 8, 72, 584, 4680, 37448; total 299592.

#define SIGLEN 299592

__global__ __launch_bounds__(256) void sigjoin_kernel(
    const float* __restrict__ x, const float* __restrict__ y,
    float* __restrict__ out)
{
    __shared__ float sy[8];   // y values for this row
    __shared__ float sf[8];   // sf[n] = 1/n!
    const int row = blockIdx.y;
    if (threadIdx.x < 8) {
        sy[threadIdx.x] = y[row * 8 + threadIdx.x];
        const float f[8] = {1.f, 1.f, 0.5f, 1.f/6.f, 1.f/24.f,
                            1.f/120.f, 1.f/720.f, 1.f/5040.f};
        sf[threadIdx.x] = f[threadIdx.x];
    }
    __syncthreads();

    const int g   = blockIdx.x * blockDim.x + threadIdx.x;  // float4 group id
    const int col = g * 4;
    if (col >= SIGLEN) return;

    const float* __restrict__ xrow = x   + (size_t)row * SIGLEN;
    float* __restrict__       orow = out + (size_t)row * SIGLEN;

    // level k and its start offset (groups of 4 never straddle levels:
    // all level starts are multiples of 8)
    int k, loff;
    if      (col >= 37448) { k = 6; loff = 37448; }
    else if (col >=  4680) { k = 5; loff =  4680; }
    else if (col >=   584) { k = 4; loff =   584; }
    else if (col >=    72) { k = 3; loff =    72; }
    else if (col >=     8) { k = 2; loff =     8; }
    else                   { k = 1; loff =     0; }

    const int j  = col - loff;   // local index within level, multiple of 4
    const int d0 = j & 7;        // last base-8 digit of the first element (0 or 4)
    int tt = j >> 3;             // prefix index for level k-1

    // S = sum_{i=0}^{k-1} x_i[prefix_i] * Q_i / (k-i)!   (x_0 = 1, Q_i = prod
    // of y over digits i+1..k-1; the shared last-digit factor y[j_k] applied later)
    float S = 0.f;
    float Q = 1.f;
    int   O = (loff >> 3) - 1;   // start offset of level k-1 (O_{i-1} = O_i/8 - 1)
    for (int i = k - 1; i >= 1; --i) {
        S += xrow[O + tt] * Q * sf[k - i];
        Q *= sy[tt & 7];
        tt >>= 3;
        O = (O >> 3) - 1;
    }
    S += Q * sf[k];              // i = 0 term: e_k (sans last-digit factor)

    const float4 xv = *(const float4*)(xrow + col);
    float4 zv;
    zv.x = xv.x + S * sy[d0 + 0];
    zv.y = xv.y + S * sy[d0 + 1];
    zv.z = xv.z + S * sy[d0 + 2];
    zv.w = xv.w + S * sy[d0 + 3];
    *(float4*)(orow + col) = zv;
}

extern "C" void kernel_launch(void* const* d_in, const int* in_sizes, int n_in,
                              void* d_out, int out_size, void* d_ws, size_t ws_size,
                              hipStream_t stream) {
    const float* x = (const float*)d_in[0];
    const float* y = (const float*)d_in[1];
    float* out = (float*)d_out;

    const int groups = SIGLEN / 4;                 // 74898
    const int bx = (groups + 255) / 256;           // 293
    dim3 grid(bx, 128, 1);
    dim3 block(256, 1, 1);
    hipLaunchKernelGGL(sigjoin_kernel, grid, block, 0, stream, x, y, out);
}

// Round 2
// 268.742 us; speedup vs baseline: 1.0716x; 1.0716x over previous
//
#include <hip/hip_runtime.h>

// SigJoin (Chen's identity), D=8, M=6, BATCH=128.
// Level start offsets O_i = (8^i - 8)/7: 0, 8, 72, 584, 4680, 37448; total 299592.
//
// Level 6 (87.5% of data) path: per-block hierarchical Horner in LDS.
//   G_L(p) = x_L[p]/(6-L)! + y[p&7] * G_{L-1}(p>>3),  G_0 = 1/6!
//   z_6[j] = x_6[j] + y[j&7] * G_5(j>>3)
// Levels 1..5: per-thread short Horner loop (old path).

#define SIGLEN 299592
#define L6_OFF 37448
#define NAIVE_BLOCKS 37   // ceil((37448/4)/256) blocks cover levels 1..5

__global__ __launch_bounds__(256) void sigjoin_kernel(
    const float* __restrict__ x, const float* __restrict__ y,
    float* __restrict__ out)
{
    __shared__ float sy[8];
    __shared__ float sf[8];
    __shared__ float sG3[2];
    __shared__ float sG4[16];
    __shared__ float sG5[128];

    const int row = blockIdx.y;
    const int tid = threadIdx.x;
    if (tid < 8) {
        sy[tid] = y[row * 8 + tid];
        const float f[8] = {1.f, 1.f, 0.5f, 1.f/6.f, 1.f/24.f,
                            1.f/120.f, 1.f/720.f, 1.f/5040.f};
        sf[tid] = f[tid];
    }
    __syncthreads();

    const float* __restrict__ xrow = x   + (size_t)row * SIGLEN;
    float* __restrict__       orow = out + (size_t)row * SIGLEN;

    if (blockIdx.x >= NAIVE_BLOCKS) {
        // ---- level-6 hierarchical path: 1024 consecutive outputs per block ----
        const int base6 = (blockIdx.x - NAIVE_BLOCKS) * 1024;  // 1024-aligned

        if (tid == 0) {
            const int p  = base6 >> 15;  // 1-digit prefix
            const int w  = base6 >> 12;  // 2-digit prefix (single value)
            const int v0 = base6 >> 9;   // 3-digit prefix base (even)
            // independent loads, one wait
            const float x1v = xrow[p];
            const float x2v = xrow[8 + w];
            const float x3a = xrow[72 + v0];
            const float x3b = xrow[72 + v0 + 1];
            const float G0 = 1.f / 720.f;
            const float G1 = x1v * (1.f/120.f) + sy[p & 7] * G0;
            const float G2 = x2v * (1.f/24.f)  + sy[w & 7] * G1;
            sG3[0] = x3a * (1.f/6.f) + sy[v0 & 7] * G2;
            sG3[1] = x3b * (1.f/6.f) + sy[(v0 + 1) & 7] * G2;
        }
        __syncthreads();
        if (tid < 16) {
            const int u0 = base6 >> 6;   // 16-aligned
            sG4[tid] = xrow[584 + u0 + tid] * 0.5f + sy[tid & 7] * sG3[tid >> 3];
        }
        __syncthreads();
        if (tid < 128) {
            const int t0 = base6 >> 3;   // 128-aligned
            sG5[tid] = xrow[4680 + t0 + tid] + sy[tid & 7] * sG4[tid >> 3];
        }
        __syncthreads();

        const int j  = base6 + tid * 4;
        const float S = sG5[tid >> 1];       // broadcast pairs, conflict-free
        const int d0 = (tid & 1) * 4;
        const float4 xv = *(const float4*)(xrow + L6_OFF + j);
        float4 zv;
        zv.x = xv.x + S * sy[d0 + 0];
        zv.y = xv.y + S * sy[d0 + 1];
        zv.z = xv.z + S * sy[d0 + 2];
        zv.w = xv.w + S * sy[d0 + 3];
        *(float4*)(orow + L6_OFF + j) = zv;
    } else {
        // ---- levels 1..5: per-thread Horner loop ----
        const int g   = blockIdx.x * 256 + tid;
        const int col = g * 4;
        if (col >= L6_OFF) return;

        int k, loff;
        if      (col >= 4680) { k = 5; loff = 4680; }
        else if (col >=  584) { k = 4; loff =  584; }
        else if (col >=   72) { k = 3; loff =   72; }
        else if (col >=    8) { k = 2; loff =    8; }
        else                  { k = 1; loff =    0; }

        const int j  = col - loff;
        const int d0 = j & 7;
        int tt = j >> 3;

        float S = 0.f;
        float Q = 1.f;
        int   O = (loff >> 3) - 1;
        for (int i = k - 1; i >= 1; --i) {
            S += xrow[O + tt] * Q * sf[k - i];
            Q *= sy[tt & 7];
            tt >>= 3;
            O = (O >> 3) - 1;
        }
        S += Q * sf[k];

        const float4 xv = *(const float4*)(xrow + col);
        float4 zv;
        zv.x = xv.x + S * sy[d0 + 0];
        zv.y = xv.y + S * sy[d0 + 1];
        zv.z = xv.z + S * sy[d0 + 2];
        zv.w = xv.w + S * sy[d0 + 3];
        *(float4*)(orow + col) = zv;
    }
}

extern "C" void kernel_launch(void* const* d_in, const int* in_sizes, int n_in,
                              void* d_out, int out_size, void* d_ws, size_t ws_size,
                              hipStream_t stream) {
    const float* x = (const float*)d_in[0];
    const float* y = (const float*)d_in[1];
    float* out = (float*)d_out;

    // 37 naive blocks (levels 1..5) + 256 hierarchical blocks (level 6) per row
    dim3 grid(NAIVE_BLOCKS + 256, 128, 1);
    dim3 block(256, 1, 1);
    hipLaunchKernelGGL(sigjoin_kernel, grid, block, 0, stream, x, y, out);
}

// Round 4
// 262.323 us; speedup vs baseline: 1.0979x; 1.0245x over previous
//
#include <hip/hip_runtime.h>

// SigJoin (Chen's identity), D=8, M=6, BATCH=128.
// z_K[j] = x_K[j] + y[j&7] * S,  S = sum_{i=0}^{K-1} x_i[j>>3(K-i)] * Q_i / (K-i)!
// (x_0 = 1, Q_i = prod of y over the digits between level i and the last digit).
// Level start offsets LOFF[k] = (8^k - 8)/7: 0, 8, 72, 584, 4680, 37448.
// Flat kernel, 8 consecutive outputs per thread (one shared S), fully unrolled
// per-level prefix chains -> all prefix loads issued independently, no barriers.

#define SIGLEN 299592

typedef float v4f __attribute__((ext_vector_type(4)));  // native vector for nontemporal builtins

__device__ constexpr float INV_FACT[8] = {1.f, 1.f, 0.5f, 1.f/6.f, 1.f/24.f,
                                          1.f/120.f, 1.f/720.f, 1.f/5040.f};
__device__ constexpr int LOFF[7] = {0, 0, 8, 72, 584, 4680, 37448};

template<int K>
__device__ __forceinline__ float prefix_S(const float* __restrict__ xrow,
                                          const float* sy, int col) {
    int tt = (col - LOFF[K]) >> 3;   // prefix index at level K-1
    float S = 0.f, Q = 1.f;
#pragma unroll
    for (int i = K - 1; i >= 1; --i) {
        S += xrow[LOFF[i] + tt] * (INV_FACT[K - i] * Q);
        Q *= sy[tt & 7];
        tt >>= 3;
    }
    S += Q * INV_FACT[K];            // e_K term (x_0 = 1)
    return S;
}

__global__ __launch_bounds__(256) void sigjoin_kernel(
    const float* __restrict__ x, const float* __restrict__ y,
    float* __restrict__ out)
{
    __shared__ float sy[8];
    const int row = blockIdx.y;
    const int tid = threadIdx.x;
    if (tid < 8) sy[tid] = y[row * 8 + tid];
    __syncthreads();

    const int col = (blockIdx.x * 256 + tid) * 8;   // 8 outputs per thread
    if (col >= SIGLEN) return;

    const float* __restrict__ xrow = x   + (size_t)row * SIGLEN;
    float* __restrict__       orow = out + (size_t)row * SIGLEN;

    float S;
    if      (col >= 37448) S = prefix_S<6>(xrow, sy, col);
    else if (col >=  4680) S = prefix_S<5>(xrow, sy, col);
    else if (col >=   584) S = prefix_S<4>(xrow, sy, col);
    else if (col >=    72) S = prefix_S<3>(xrow, sy, col);
    else if (col >=     8) S = prefix_S<2>(xrow, sy, col);
    else                   S = 1.f;   // level 1: z = x + y

    // stream 8 elements: z[col+d] = x[col+d] + S * sy[d], d = 0..7
    const v4f xa = __builtin_nontemporal_load((const v4f*)(xrow + col));
    const v4f xb = __builtin_nontemporal_load((const v4f*)(xrow + col + 4));
    const v4f ya = *(const v4f*)(&sy[0]);
    const v4f yb = *(const v4f*)(&sy[4]);
    v4f za = xa + S * ya;
    v4f zb = xb + S * yb;
    __builtin_nontemporal_store(za, (v4f*)(orow + col));
    __builtin_nontemporal_store(zb, (v4f*)(orow + col + 4));
}

extern "C" void kernel_launch(void* const* d_in, const int* in_sizes, int n_in,
                              void* d_out, int out_size, void* d_ws, size_t ws_size,
                              hipStream_t stream) {
    const float* x = (const float*)d_in[0];
    const float* y = (const float*)d_in[1];
    float* out = (float*)d_out;

    const int groups = SIGLEN / 8;            // 37449 threads per row
    const int bx = (groups + 255) / 256;      // 147
    dim3 grid(bx, 128, 1);
    dim3 block(256, 1, 1);
    hipLaunchKernelGGL(sigjoin_kernel, grid, block, 0, stream, x, y, out);
}